// Round 15
// baseline (237.166 us; speedup 1.0000x reference)
//
#include <hip/hip_runtime.h>
#include <hip/hip_fp16.h>

using i32x4  = __attribute__((ext_vector_type(4)))  int;
using i32x16 = __attribute__((ext_vector_type(16))) int;

static constexpr int M  = 4 * 2048;   // 8192 rows (B*S)
static constexpr int N  = 4096;       // OUT_F
static constexpr int K  = 4096;       // IN_F
static constexpr int BM = 128, BN = 128, BK = 64;
static constexpr int NT = K / BK;     // 64 K-tiles
static constexpr int TILE = BM * BK;  // 8192 bytes per packed int8 tile

// ---------------- fused pack kernel: int32 -> blocked int8 tiles -------------
// tile (8 KB): [kg(4)][row(128)][16B]  wa: [M/128][NT][tile], wb: [N/128][NT][tile]
static constexpr int PX_BLOCKS = (int)((size_t)M * K / 16 / 256);  // 8192
static constexpr int PW_BLOCKS = (int)((size_t)N * K / 16 / 256);  // 4096

__device__ __forceinline__ unsigned pack4(i32x4 v) {
  return (unsigned)((v.x & 255) | ((v.y & 255) << 8) | ((v.z & 255) << 16) | (v.w << 24));
}

__global__ __launch_bounds__(256) void pack_kernel(const int* __restrict__ x,
                                                   const int* __restrict__ w,
                                                   unsigned char* __restrict__ wa,
                                                   unsigned char* __restrict__ wb) {
  if (blockIdx.x < PX_BLOCKS) {
    unsigned g = blockIdx.x * 256 + threadIdx.x;     // dest 16B granule, < M*K/16
    unsigned tile = g >> 9, gt = g & 511;
    unsigned kg = gt >> 7, row = gt & 127;
    unsigned br = tile >> 6, kt = tile & 63;
    const int* src = x + ((size_t)(br * 128 + row) * K + kt * 64 + kg * 16);
    i32x4 v0 = *(const i32x4*)(src + 0);
    i32x4 v1 = *(const i32x4*)(src + 4);
    i32x4 v2 = *(const i32x4*)(src + 8);
    i32x4 v3 = *(const i32x4*)(src + 12);
    i32x4 d;
    d.x = (int)pack4(v0); d.y = (int)pack4(v1); d.z = (int)pack4(v2); d.w = (int)pack4(v3);
    *(i32x4*)(wa + (size_t)g * 16) = d;
  } else {
    unsigned g = (blockIdx.x - PX_BLOCKS) * 256 + threadIdx.x;  // < N*K/16
    unsigned tile = g >> 9, gt = g & 511;
    unsigned kg = gt >> 7, col = gt & 127;
    unsigned bn = tile >> 6, kt = tile & 63;
    unsigned n  = bn * 128 + col;
    unsigned k0 = kt * 64 + kg * 16;
    const int* src = w + (size_t)k0 * N + n;
    i32x4 d;
#pragma unroll
    for (int j = 0; j < 4; ++j) {
      int b0 = src[(size_t)(j * 4 + 0) * N];
      int b1 = src[(size_t)(j * 4 + 1) * N];
      int b2 = src[(size_t)(j * 4 + 2) * N];
      int b3 = src[(size_t)(j * 4 + 3) * N];
      d[j] = (b0 & 255) | ((b1 & 255) << 8) | ((b2 & 255) << 16) | (b3 << 24);
    }
    *(i32x4*)(wb + (size_t)g * 16) = d;
  }
}

// -- GEMM: 128x128, 4 waves (2x2), A reg-staged LDS @ dist 2, B direct,  ------
//    WAVE-STAGGERED kc order (w&1) to break post-barrier request convoys;
//    raw s_barrier + lgkmcnt(0) only (vmcnt never drained mid-loop).

#define SBAR()  do { __builtin_amdgcn_sched_barrier(0);                         \
                     asm volatile("s_waitcnt lgkmcnt(0)" ::: "memory");         \
                     __builtin_amdgcn_s_barrier();                              \
                     __builtin_amdgcn_sched_barrier(0); } while (0)

__global__ __launch_bounds__(256) void gemm_i8(const unsigned char* __restrict__ wa,
                                               const unsigned char* __restrict__ wb,
                                               const __half* __restrict__ bias,
                                               const float* __restrict__ alphaP,
                                               float* __restrict__ out) {
  __shared__ __align__(16) unsigned char As[2][TILE];   // 16 KB total (A only)

  const int tid  = threadIdx.x;
  const int lane = tid & 63;
  const int w    = tid >> 6;            // wave 0..3
  const int wr   = w >> 1, wc = w & 1;  // 2 x 2 grid; wave tile 64 x 64
  const int l31  = lane & 31;
  const int kgl  = lane >> 5;
  const bool phi = (w & 1) != 0;        // wave-uniform phase: kc order stagger

  const int bc = blockIdx.x;            // 0..31 (fast: neighbors share A panel)
  const int br = blockIdx.y;            // 0..63

  const unsigned char* ga = wa + (size_t)br * NT * TILE;
  const unsigned char* gb = wb + (size_t)bc * NT * TILE;

  const int arow = wr * 64 + l31;       // A frag row base (per lane)
  const int bcol = wc * 64 + l31;       // B frag col base (per lane)

  // A staging sets (distance 2): P = even tiles, Q = odd tiles
  i32x4 p0, p1, q0, q1;
  // B direct regs: [parity][kc][ni], all indices compile-time constant
  i32x4 b[2][2][2];

#define GLOADA_P(T) do {                                             \
    const i32x4* ap = (const i32x4*)(ga + (size_t)(T) * TILE);       \
    p0 = ap[tid]; p1 = ap[tid + 256];                                \
  } while (0)

#define GLOADA_Q(T) do {                                             \
    const i32x4* ap = (const i32x4*)(ga + (size_t)(T) * TILE);       \
    q0 = ap[tid]; q1 = ap[tid + 256];                                \
  } while (0)

#define SWRITE_P(BUF) do {                                           \
    i32x4* aw = (i32x4*)&As[BUF][0];                                 \
    aw[tid] = p0; aw[tid + 256] = p1;                                \
  } while (0)

#define SWRITE_Q(BUF) do {                                           \
    i32x4* aw = (i32x4*)&As[BUF][0];                                 \
    aw[tid] = q0; aw[tid + 256] = q1;                                \
  } while (0)

#define BLOAD_KC(PAR, KC, T) do {                                    \
    const unsigned char* bt = gb + (size_t)(T) * TILE + ((KC) * 2 + kgl) * 2048; \
    b[PAR][KC][0] = *(const i32x4*)(bt + (bcol +  0) * 16);          \
    b[PAR][KC][1] = *(const i32x4*)(bt + (bcol + 32) * 16);          \
  } while (0)

  i32x16 acc[2][2] = {};

  // one kc chunk: 2 A-frag reads + 4 MFMAs (indices compile-time)
#define CHUNK(BUF, PAR, KC) do {                                               \
    const unsigned char* Ap = &As[BUF][0] + (((KC) * 2) + kgl) * 2048;         \
    i32x4 a0 = *(const i32x4*)(Ap + (arow +  0) * 16);                         \
    i32x4 a1 = *(const i32x4*)(Ap + (arow + 32) * 16);                         \
    acc[0][0] = __builtin_amdgcn_mfma_i32_32x32x32_i8(a0, b[PAR][KC][0], acc[0][0], 0, 0, 0); \
    acc[0][1] = __builtin_amdgcn_mfma_i32_32x32x32_i8(a0, b[PAR][KC][1], acc[0][1], 0, 0, 0); \
    acc[1][0] = __builtin_amdgcn_mfma_i32_32x32x32_i8(a1, b[PAR][KC][0], acc[1][0], 0, 0, 0); \
    acc[1][1] = __builtin_amdgcn_mfma_i32_32x32x32_i8(a1, b[PAR][KC][1], acc[1][1], 0, 0, 0); \
  } while (0)

  // staggered tile body: even waves kc0->kc1, odd waves kc1->kc0 (exact: int sum)
#define BODY(BUF, PAR, T) do {                                                 \
    if (!phi) {                                                                \
      CHUNK(BUF, PAR, 0); if ((T) + 2 < NT) BLOAD_KC(PAR, 0, (T) + 2);         \
      CHUNK(BUF, PAR, 1); if ((T) + 2 < NT) BLOAD_KC(PAR, 1, (T) + 2);         \
    } else {                                                                   \
      CHUNK(BUF, PAR, 1); if ((T) + 2 < NT) BLOAD_KC(PAR, 1, (T) + 2);         \
      CHUNK(BUF, PAR, 0); if ((T) + 2 < NT) BLOAD_KC(PAR, 0, (T) + 2);         \
    }                                                                          \
  } while (0)

  // prologue: A(0)->LDS buf0; A(1) in flight (Q); B(0) par0, B(1) par1
  GLOADA_P(0);
  BLOAD_KC(0, 0, 0); BLOAD_KC(0, 1, 0);
  SWRITE_P(0);        // compiler inserts counted vmcnt for p* before ds_writes
  GLOADA_Q(1);
  BLOAD_KC(1, 0, 1); BLOAD_KC(1, 1, 1);
  __syncthreads();    // single full drain before the loop

  for (int t = 0; t < NT; t += 2) {
    // even tile t: compute buf0/par0; prefetch A(t+2)->P, B(t+2)->par0
    if (t + 2 < NT) GLOADA_P(t + 2);
    BODY(0, 0, t);
    __builtin_amdgcn_sched_barrier(0);   // keep SWRITE's wait out of the MFMAs
    if (t + 1 < NT) SWRITE_Q(1);         // A(t+1), loaded at t-1 (2 steps in flight)
    SBAR();                              // lgkmcnt(0)+barrier; vmcnt NOT drained

    // odd tile t+1: compute buf1/par1; prefetch A(t+3)->Q, B(t+3)->par1
    if (t + 3 < NT) GLOADA_Q(t + 3);
    BODY(1, 1, t + 1);
    __builtin_amdgcn_sched_barrier(0);
    if (t + 2 < NT) SWRITE_P(0);         // A(t+2), loaded at t
    SBAR();
  }

  // epilogue: C/D layout col=lane&31, row=(r&3)+8*(r>>2)+4*(lane>>5)
  const float alpha = *alphaP;
  const int row0 = br * 128 + wr * 64 + 4 * kgl;
  const int col0 = bc * 128 + wc * 64 + l31;
#pragma unroll
  for (int ni = 0; ni < 2; ++ni) {
    const int col = col0 + ni * 32;
    const float bf = __half2float(bias[col]);
#pragma unroll
    for (int mi = 0; mi < 2; ++mi) {
#pragma unroll
      for (int r = 0; r < 16; ++r) {
        const int row = row0 + mi * 32 + (r & 3) + 8 * (r >> 2);
        out[(size_t)row * N + col] = ((float)acc[mi][ni][r] + bf) * alpha;
      }
    }
  }
#undef BODY
#undef CHUNK
#undef GLOADA_P
#undef GLOADA_Q
#undef SWRITE_P
#undef SWRITE_Q
#undef BLOAD_KC
}

extern "C" void kernel_launch(void* const* d_in, const int* in_sizes, int n_in,
                              void* d_out, int out_size, void* d_ws, size_t ws_size,
                              hipStream_t stream) {
  const int*    x     = (const int*)d_in[0];
  const int*    wgt   = (const int*)d_in[1];
  const __half* bias  = (const __half*)d_in[2];
  const float*  alpha = (const float*)d_in[3];
  float*        out   = (float*)d_out;

  // workspace: packed A (32 MB) + packed B (16 MB) = 48 MB
  unsigned char* wa = (unsigned char*)d_ws;
  unsigned char* wb = wa + (size_t)M * K;

  pack_kernel<<<PX_BLOCKS + PW_BLOCKS, 256, 0, stream>>>(x, wgt, wa, wb);

  dim3 grid(N / BN, M / BM);   // 32 x 64 = 2048 blocks
  gemm_i8<<<grid, 256, 0, stream>>>(wa, wb, bias, alpha, out);
}

// Round 16
// 220.227 us; speedup vs baseline: 1.0769x; 1.0769x over previous
//
#include <hip/hip_runtime.h>
#include <hip/hip_fp16.h>

using i32x4  = __attribute__((ext_vector_type(4)))  int;
using i32x16 = __attribute__((ext_vector_type(16))) int;

static constexpr int M  = 4 * 2048;   // 8192 rows (B*S)
static constexpr int N  = 4096;       // OUT_F
static constexpr int K  = 4096;       // IN_F
static constexpr int BM = 256, BN = 128, BK = 64;   // block: 4 waves (2x2), wave 128x64
static constexpr int NT = K / BK;     // 64 K-tiles
static constexpr int TILE = 128 * BK; // 8192 B packed int8 panel-tile (128 rows/cols)

// ---------------- fused pack kernel: int32 -> blocked int8 tiles -------------
// tile (8 KB): [kg(4)][row(128)][16B]  wa: [M/128][NT][tile], wb: [N/128][NT][tile]
static constexpr int PX_BLOCKS = (int)((size_t)M * K / 16 / 256);  // 8192
static constexpr int PW_BLOCKS = (int)((size_t)N * K / 16 / 256);  // 4096

__device__ __forceinline__ unsigned pack4(i32x4 v) {
  return (unsigned)((v.x & 255) | ((v.y & 255) << 8) | ((v.z & 255) << 16) | (v.w << 24));
}

__global__ __launch_bounds__(256) void pack_kernel(const int* __restrict__ x,
                                                   const int* __restrict__ w,
                                                   unsigned char* __restrict__ wa,
                                                   unsigned char* __restrict__ wb) {
  if (blockIdx.x < PX_BLOCKS) {
    unsigned g = blockIdx.x * 256 + threadIdx.x;     // dest 16B granule, < M*K/16
    unsigned tile = g >> 9, gt = g & 511;
    unsigned kg = gt >> 7, row = gt & 127;
    unsigned br = tile >> 6, kt = tile & 63;
    const int* src = x + ((size_t)(br * 128 + row) * K + kt * 64 + kg * 16);
    i32x4 v0 = *(const i32x4*)(src + 0);
    i32x4 v1 = *(const i32x4*)(src + 4);
    i32x4 v2 = *(const i32x4*)(src + 8);
    i32x4 v3 = *(const i32x4*)(src + 12);
    i32x4 d;
    d.x = (int)pack4(v0); d.y = (int)pack4(v1); d.z = (int)pack4(v2); d.w = (int)pack4(v3);
    *(i32x4*)(wa + (size_t)g * 16) = d;
  } else {
    unsigned g = (blockIdx.x - PX_BLOCKS) * 256 + threadIdx.x;  // < N*K/16
    unsigned tile = g >> 9, gt = g & 511;
    unsigned kg = gt >> 7, col = gt & 127;
    unsigned bn = tile >> 6, kt = tile & 63;
    unsigned n  = bn * 128 + col;
    unsigned k0 = kt * 64 + kg * 16;
    const int* src = w + (size_t)k0 * N + n;
    i32x4 d;
#pragma unroll
    for (int j = 0; j < 4; ++j) {
      int b0 = src[(size_t)(j * 4 + 0) * N];
      int b1 = src[(size_t)(j * 4 + 1) * N];
      int b2 = src[(size_t)(j * 4 + 2) * N];
      int b3 = src[(size_t)(j * 4 + 3) * N];
      d[j] = (b0 & 255) | ((b1 & 255) << 8) | ((b2 & 255) << 16) | (b3 << 24);
    }
    *(i32x4*)(wb + (size_t)g * 16) = d;
  }
}

// -- GEMM: NO LDS, NO BARRIERS. All fragments global->VGPR, coalesced. -------
// 4 waves (2x2), wave tile 128x64 (acc[4][2]); reg double-buffer, distance 2.

__global__ __launch_bounds__(256, 2) void gemm_i8(const unsigned char* __restrict__ wa,
                                                  const unsigned char* __restrict__ wb,
                                                  const __half* __restrict__ bias,
                                                  const float* __restrict__ alphaP,
                                                  float* __restrict__ out) {
  const int tid  = threadIdx.x;
  const int lane = tid & 63;
  const int w    = tid >> 6;            // wave 0..3
  const int wr   = w >> 1, wc = w & 1;  // 2 x 2 grid; wave tile 128 x 64
  const int l31  = lane & 31;
  const int kgl  = lane >> 5;

  const int bc = blockIdx.x;            // 0..31 (fast: neighbors share A panels)
  const int br = blockIdx.y;            // 0..31

  // per-wave A panel (128 rows) and B panel slice
  const unsigned char* gaw = wa + (size_t)(br * 2 + wr) * NT * TILE;
  const unsigned char* gbw = wb + (size_t)bc * NT * TILE;

  // constant per-lane byte offsets within a tile (kc0; kc1 = +4096)
  const int aoff = kgl * 2048 + l31 * 16;              // + {0,512,1024,1536}
  const int boff = kgl * 2048 + (wc * 64 + l31) * 16;  // + {0,512}

  // stage sets: P = even tiles, Q = odd tiles. 24 named regs (rule #20).
  i32x4 pA0, pA1, pA2, pA3, pB0, pB1;   // kc0
  i32x4 pC0, pC1, pC2, pC3, pD0, pD1;   // kc1
  i32x4 qA0, qA1, qA2, qA3, qB0, qB1;
  i32x4 qC0, qC1, qC2, qC3, qD0, qD1;

#define LOAD_P(T) do {                                               \
    const unsigned char* at = gaw + (size_t)(T) * TILE;              \
    const unsigned char* bt = gbw + (size_t)(T) * TILE;              \
    pA0 = *(const i32x4*)(at + aoff +    0);                         \
    pA1 = *(const i32x4*)(at + aoff +  512);                         \
    pA2 = *(const i32x4*)(at + aoff + 1024);                         \
    pA3 = *(const i32x4*)(at + aoff + 1536);                         \
    pB0 = *(const i32x4*)(bt + boff +    0);                         \
    pB1 = *(const i32x4*)(bt + boff +  512);                         \
    pC0 = *(const i32x4*)(at + 4096 + aoff +    0);                  \
    pC1 = *(const i32x4*)(at + 4096 + aoff +  512);                  \
    pC2 = *(const i32x4*)(at + 4096 + aoff + 1024);                  \
    pC3 = *(const i32x4*)(at + 4096 + aoff + 1536);                  \
    pD0 = *(const i32x4*)(bt + 4096 + boff +    0);                  \
    pD1 = *(const i32x4*)(bt + 4096 + boff +  512);                  \
  } while (0)

#define LOAD_Q(T) do {                                               \
    const unsigned char* at = gaw + (size_t)(T) * TILE;              \
    const unsigned char* bt = gbw + (size_t)(T) * TILE;              \
    qA0 = *(const i32x4*)(at + aoff +    0);                         \
    qA1 = *(const i32x4*)(at + aoff +  512);                         \
    qA2 = *(const i32x4*)(at + aoff + 1024);                         \
    qA3 = *(const i32x4*)(at + aoff + 1536);                         \
    qB0 = *(const i32x4*)(bt + boff +    0);                         \
    qB1 = *(const i32x4*)(bt + boff +  512);                         \
    qC0 = *(const i32x4*)(at + 4096 + aoff +    0);                  \
    qC1 = *(const i32x4*)(at + 4096 + aoff +  512);                  \
    qC2 = *(const i32x4*)(at + 4096 + aoff + 1024);                  \
    qC3 = *(const i32x4*)(at + 4096 + aoff + 1536);                  \
    qD0 = *(const i32x4*)(bt + 4096 + boff +    0);                  \
    qD1 = *(const i32x4*)(bt + 4096 + boff +  512);                  \
  } while (0)

  i32x16 acc[4][2] = {};

#define MF(mi, ni, A, B) \
  acc[mi][ni] = __builtin_amdgcn_mfma_i32_32x32x32_i8(A, B, acc[mi][ni], 0, 0, 0)

#define COMPUTE_P() do {                                             \
    MF(0, 0, pA0, pB0); MF(0, 1, pA0, pB1);                          \
    MF(1, 0, pA1, pB0); MF(1, 1, pA1, pB1);                          \
    MF(2, 0, pA2, pB0); MF(2, 1, pA2, pB1);                          \
    MF(3, 0, pA3, pB0); MF(3, 1, pA3, pB1);                          \
    MF(0, 0, pC0, pD0); MF(0, 1, pC0, pD1);                          \
    MF(1, 0, pC1, pD0); MF(1, 1, pC1, pD1);                          \
    MF(2, 0, pC2, pD0); MF(2, 1, pC2, pD1);                          \
    MF(3, 0, pC3, pD0); MF(3, 1, pC3, pD1);                          \
  } while (0)

#define COMPUTE_Q() do {                                             \
    MF(0, 0, qA0, qB0); MF(0, 1, qA0, qB1);                          \
    MF(1, 0, qA1, qB0); MF(1, 1, qA1, qB1);                          \
    MF(2, 0, qA2, qB0); MF(2, 1, qA2, qB1);                          \
    MF(3, 0, qA3, qB0); MF(3, 1, qA3, qB1);                          \
    MF(0, 0, qC0, qD0); MF(0, 1, qC0, qD1);                          \
    MF(1, 0, qC1, qD0); MF(1, 1, qC1, qD1);                          \
    MF(2, 0, qC2, qD0); MF(2, 1, qC2, qD1);                          \
    MF(3, 0, qC3, qD0); MF(3, 1, qC3, qD1);                          \
  } while (0)

  // prologue: tiles 0 (P) and 1 (Q) in flight; no barrier anywhere
  LOAD_P(0);
  LOAD_Q(1);

  for (int t = 0; t < NT; t += 2) {
    COMPUTE_P();                     // waits (counted vmcnt) on P only
    if (t + 2 < NT) LOAD_P(t + 2);   // P regs free; 2 tiles of compute in flight
    COMPUTE_Q();
    if (t + 3 < NT) LOAD_Q(t + 3);
  }

  // epilogue: C/D layout col=lane&31, row=(r&3)+8*(r>>2)+4*(lane>>5)
  const float alpha = *alphaP;
  const int row0 = br * 256 + wr * 128 + 4 * kgl;
  const int col0 = bc * 128 + wc * 64 + l31;
#pragma unroll
  for (int ni = 0; ni < 2; ++ni) {
    const int col = col0 + ni * 32;
    const float bf = __half2float(bias[col]);
#pragma unroll
    for (int mi = 0; mi < 4; ++mi) {
#pragma unroll
      for (int r = 0; r < 16; ++r) {
        const int row = row0 + mi * 32 + (r & 3) + 8 * (r >> 2);
        out[(size_t)row * N + col] = ((float)acc[mi][ni][r] + bf) * alpha;
      }
    }
  }
#undef COMPUTE_P
#undef COMPUTE_Q
#undef MF
#undef LOAD_P
#undef LOAD_Q
}

extern "C" void kernel_launch(void* const* d_in, const int* in_sizes, int n_in,
                              void* d_out, int out_size, void* d_ws, size_t ws_size,
                              hipStream_t stream) {
  const int*    x     = (const int*)d_in[0];
  const int*    wgt   = (const int*)d_in[1];
  const __half* bias  = (const __half*)d_in[2];
  const float*  alpha = (const float*)d_in[3];
  float*        out   = (float*)d_out;

  // workspace: packed A (32 MB) + packed B (16 MB) = 48 MB
  unsigned char* wa = (unsigned char*)d_ws;
  unsigned char* wb = wa + (size_t)M * K;

  pack_kernel<<<PX_BLOCKS + PW_BLOCKS, 256, 0, stream>>>(x, wgt, wa, wb);

  dim3 grid(N / BN, M / BM);   // 32 x 32 = 1024 blocks
  gemm_i8<<<grid, 256, 0, stream>>>(wa, wb, bias, alpha, out);
}